// Round 16
// baseline (1011.328 us; speedup 1.0000x reference)
//
#include <hip/hip_runtime.h>
#include <hip/hip_bf16.h>
#include <math.h>

#define NROW   8192      // B*H*W z-rows
#define KCODE  8192      // codebook entries
#define CD     256
#define HWSZ   1024
#define NBLK   64        // 128-code blocks (R5/R10-proven pK layout)
#define MARGIN 7.5e-5f

#define QOFF   ((size_t)NROW * CD)   // 2097152: loss at QOFF, indices at QOFF+1

typedef __attribute__((ext_vector_type(8)))  short short8;
typedef __attribute__((ext_vector_type(16))) float f32x16;
typedef unsigned long long u64;

// LDS layout (bytes)
#define AS_OFF 0                         // bf16 A: 128 codes x 136B
#define BS_OFF 17408                     // bf16 B: 128 rows  x 136B
#define XS_OFF 34816                     // fp32 xs: [64k][132f]
#define ES_OFF 68608                     // fp32 es: [64k][132f]
#define SM_BYTES 102400

// sortable key: high32 = monotone float map, low32 = code (lex tie -> low index)
__device__ __forceinline__ u64 makeKey(float v, int code) {
  unsigned u = __float_as_uint(v);
  unsigned m = (u & 0x80000000u) ? ~u : (u | 0x80000000u);
  return ((u64)m << 32) | (unsigned)code;
}
__device__ __forceinline__ float keyVal(u64 k) {
  unsigned m = (unsigned)(k >> 32);
  unsigned u = (m & 0x80000000u) ? (m ^ 0x80000000u) : ~m;
  return __uint_as_float(u);
}
__device__ __forceinline__ void ins3(u64 k, u64& t1, u64& t2, u64& t3) {
  if (k < t1) { t3 = t2; t2 = t1; t1 = k; }
  else if (k < t2) { t3 = t2; t2 = k; }
  else if (k < t3) { t3 = k; }
}
__device__ __forceinline__ unsigned short f2bf(float f) {
  __hip_bfloat16 h = __float2bfloat16(f);
  return *(unsigned short*)&h;
}

// ---------------- k1: z -> Xhi bf16 [n][c] (d_ws) + exact-numpy x2 (R2-proven) ------
__global__ __launch_bounds__(256) void splitz_x2_kernel(
    const float* __restrict__ z, unsigned short* __restrict__ Xhi,
    float* __restrict__ x2g) {
  __shared__ float xs[32 * 260];
  int tid = threadIdx.x;
  int n0 = blockIdx.x * 32;
  int b = n0 >> 10;
  int hw0 = n0 & 1023;
  const float* zb = z + (size_t)b * (CD * HWSZ) + hw0;
  {
    int r = tid & 31;
    int cbase = tid >> 5;
    for (int it = 0; it < 32; ++it) {
      int c = cbase + it * 8;
      xs[r * 260 + c] = zb[(size_t)c * HWSZ + r];
    }
  }
  __syncthreads();
  if (tid < 32) {
#pragma clang fp contract(off)
    const float* xr = &xs[tid * 260];
    float r0[8], r1[8];
#pragma unroll
    for (int j = 0; j < 8; ++j) {
      float v = xr[j];       r0[j] = v * v;
      float w = xr[128 + j]; r1[j] = w * w;
    }
    for (int i = 8; i < 128; i += 8) {
#pragma unroll
      for (int j = 0; j < 8; ++j) {
        float v = xr[i + j];       float a  = v * v; r0[j] = r0[j] + a;
        float w = xr[128 + i + j]; float b2 = w * w; r1[j] = r1[j] + b2;
      }
    }
    float lo = ((r0[0] + r0[1]) + (r0[2] + r0[3])) + ((r0[4] + r0[5]) + (r0[6] + r0[7]));
    float hi = ((r1[0] + r1[1]) + (r1[2] + r1[3])) + ((r1[4] + r1[5]) + (r1[6] + r1[7]));
    x2g[n0 + tid] = lo + hi;
  }
  for (int r = 0; r < 32; ++r) {
    float v = xs[r * 260 + tid];
    Xhi[(size_t)(n0 + r) * CD + tid] = f2bf(v);
  }
}

// ---------------- k2: emb -> Ehi bf16 (d_ws) ----------------
__global__ __launch_bounds__(256) void splite_kernel(
    const float* __restrict__ emb, unsigned short* __restrict__ Ehi) {
  int n = blockIdx.x * 256 + threadIdx.x;
  Ehi[n] = f2bf(emb[n]);
}

// ---------------- k3: HYBRID GEMM — MFMA waves + VALU waves on separate rows -------
// Box-law (R5-R15): MFMA pipe ~80 TF regardless of shape; VALU pipe healthy (R2).
// Per block (512 thr): 128 codes x 256 rows. Waves 0-3: MFMA (rows +0..127, bf16).
// Waves 4-7: VALU fp32 (rows +128..255, from z/emb). m114: pipes overlap per CU.
__global__ __launch_bounds__(512) void gemm_top3_kernel(
    const unsigned short* __restrict__ Eg,   // bf16 [8192][256] (d_ws)
    const unsigned short* __restrict__ Xg,   // bf16 [8192][256] (d_ws)
    const float* __restrict__ z, const float* __restrict__ emb,
    u64* __restrict__ pK1, u64* __restrict__ pK2, u64* __restrict__ pK3) {
  __shared__ __align__(16) char SM[SM_BYTES];
  int tid = threadIdx.x;
  int bid = blockIdx.x;                      // 0..2047
  int swz = (bid & 7) * 256 + (bid >> 3);    // XCD swizzle (bijective, 2048%8==0)
  int cbx = swz >> 5;                        // 0..63
  int rby = swz & 31;                        // 0..31
  int cb0 = cbx * 128, rb0 = rby * 256;
  int b = rb0 >> 10;
  int hwb = rb0 & 1023;
  int wid = tid >> 6, lane = tid & 63;
  bool isV = (wid >= 4);                     // VALU engine waves

  // --- MFMA state (waves 0-3): wave = 64 codes x 64 rows = 2x2 of 32x32 ---
  int l31 = lane & 31, lhd = lane >> 5;
  int wr = wid & 1, wc = (wid >> 1) & 1;
  f32x16 acc[2][2];
#pragma unroll
  for (int i = 0; i < 2; ++i)
#pragma unroll
    for (int j = 0; j < 2; ++j) acc[i][j] = (f32x16){};

  // --- VALU state (waves 4-7): thread = 8 codes x 8 rows ---
  int t2 = tid - 256;                        // 0..255 for VALU threads
  int cg = t2 & 15, rg = t2 >> 4;
  float vacc[64];
#pragma unroll
  for (int i = 0; i < 64; ++i) vacc[i] = 0.f;

  // staging addresses
  int srowA = (tid & 255) >> 1, soff = (tid & 1) * 64;     // MFMA threads (tid<256)
  const char* gE = (const char*)Eg + ((size_t)(cb0 + srowA)) * 512 + soff;
  const char* gX = (const char*)Xg + ((size_t)(rb0 + srowA)) * 512 + soff;
  int xc = (t2 & 255) >> 2, xo = (t2 & 3) * 32;            // VALU xs staging
  const float* gz = z + (size_t)b * (CD * HWSZ) + hwb + 128 + xo;
  int ec = (t2 & 255) >> 1, ekh = (t2 & 1) * 32;           // VALU es staging
  const float* ge = emb + (size_t)(cb0 + ec) * CD + ekh;

  for (int kc = 0; kc < 4; ++kc) {
    if (kc) __syncthreads();                 // previous chunk's reads done
    if (!isV) {
      // stage As (Ehi codes) and Bs (Xhi rows rb0..+127), 64B per thread each
#pragma unroll
      for (int q = 0; q < 4; ++q) {
        short8 va = *(const short8*)(gE + kc * 128 + q * 16);
        *(short8*)(SM + AS_OFF + srowA * 136 + soff + q * 16) = va;
      }
#pragma unroll
      for (int q = 0; q < 4; ++q) {
        short8 vb = *(const short8*)(gX + kc * 128 + q * 16);
        *(short8*)(SM + BS_OFF + srowA * 136 + soff + q * 16) = vb;
      }
    } else {
      // stage xs: fp32 z rows rb0+128..+255, [64k][128 rows]
#pragma unroll
      for (int q = 0; q < 8; ++q) {
        float4 v = *(const float4*)(gz + (size_t)(kc * 64 + xc) * HWSZ + q * 4);
        *(float4*)(SM + XS_OFF + (xc * 132 + xo + q * 4) * 4) = v;
      }
      // stage es: fp32 emb, transpose to [64k][128 codes]
      float ev[32];
#pragma unroll
      for (int q = 0; q < 8; ++q)
        *(float4*)&ev[q * 4] = *(const float4*)(ge + kc * 64 + q * 4);
#pragma unroll
      for (int q = 0; q < 32; ++q)
        *(float*)(SM + ES_OFF + ((ekh + q) * 132 + ec) * 4) = ev[q];
    }
    __syncthreads();                          // tiles ready

    if (!isV) {
#pragma unroll
      for (int ks = 0; ks < 4; ++ks) {        // K=16 per step
        short8 af[2], bf[2];
#pragma unroll
        for (int i = 0; i < 2; ++i)
          af[i] = *(const short8*)(SM + AS_OFF + (64 * wr + 32 * i + l31) * 136 + ks * 32 + lhd * 16);
#pragma unroll
        for (int j = 0; j < 2; ++j)
          bf[j] = *(const short8*)(SM + BS_OFF + (64 * wc + 32 * j + l31) * 136 + ks * 32 + lhd * 16);
#pragma unroll
        for (int i = 0; i < 2; ++i)
#pragma unroll
          for (int j = 0; j < 2; ++j)
            acc[i][j] = __builtin_amdgcn_mfma_f32_32x32x16_bf16(af[i], bf[j], acc[i][j], 0, 0, 0);
      }
    } else {
      for (int k = 0; k < 64; ++k) {
        float a8[8], b8[8];
        const float* xr = (const float*)(SM + XS_OFF) + k * 132 + rg * 8;
        *(float4*)&a8[0] = *(const float4*)(xr);
        *(float4*)&a8[4] = *(const float4*)(xr + 4);
        const float* er = (const float*)(SM + ES_OFF) + k * 132 + cg * 8;
        *(float4*)&b8[0] = *(const float4*)(er);
        *(float4*)&b8[4] = *(const float4*)(er + 4);
#pragma unroll
        for (int ii = 0; ii < 8; ++ii)
#pragma unroll
          for (int jj = 0; jj < 8; ++jj)
            vacc[ii * 8 + jj] = fmaf(a8[ii], b8[jj], vacc[ii * 8 + jj]);
      }
    }
  }
  __syncthreads();                            // compute done; overlay redK

  u64* redK = (u64*)SM;                       // [2 wr][128 rows][3] = 6 KB
  if (!isV) {
    // MFMA epilogue: 32x32 C/D (m74/m101): zrow = rb0+64wc+32j+l31,
    // code = cb0+64wr+32i+(r&3)+8(r>>2)+4lhd; xor-32 merges disjoint quartets.
#pragma unroll
    for (int j = 0; j < 2; ++j) {
      u64 k1 = ~0ull, k2 = ~0ull, k3 = ~0ull;
#pragma unroll
      for (int i = 0; i < 2; ++i)
#pragma unroll
        for (int r = 0; r < 16; ++r) {
          float v = -2.0f * acc[i][j][r];     // x2 cancels per-row; monotone
          int code = cb0 + 64 * wr + 32 * i + (r & 3) + 8 * (r >> 2) + 4 * lhd;
          ins3(makeKey(v, code), k1, k2, k3);
        }
      {
        u64 o1 = __shfl_xor(k1, 32, 64);
        u64 o2 = __shfl_xor(k2, 32, 64);
        u64 o3 = __shfl_xor(k3, 32, 64);
        ins3(o1, k1, k2, k3); ins3(o2, k1, k2, k3); ins3(o3, k1, k2, k3);
      }
      if (lhd == 0) {
        int zl = 64 * wc + 32 * j + l31;      // 0..127
        redK[(wr * 128 + zl) * 3 + 0] = k1;
        redK[(wr * 128 + zl) * 3 + 1] = k2;
        redK[(wr * 128 + zl) * 3 + 2] = k3;
      }
    }
  } else {
    // VALU epilogue: in-wave shfl merge over the 16 cg lanes (no LDS)
#pragma unroll
    for (int ii = 0; ii < 8; ++ii) {
      u64 k1 = ~0ull, k2 = ~0ull, k3 = ~0ull;
#pragma unroll
      for (int jj = 0; jj < 8; ++jj) {
        float v = -2.0f * vacc[ii * 8 + jj];
        ins3(makeKey(v, cb0 + cg * 8 + jj), k1, k2, k3);
      }
#pragma unroll
      for (int off = 1; off < 16; off <<= 1) {
        u64 o1 = __shfl_xor(k1, off, 64);
        u64 o2 = __shfl_xor(k2, off, 64);
        u64 o3 = __shfl_xor(k3, off, 64);
        ins3(o1, k1, k2, k3); ins3(o2, k1, k2, k3); ins3(o3, k1, k2, k3);
      }
      if (cg == 0) {
        size_t o = (size_t)cbx * NROW + rb0 + 128 + rg * 8 + ii;
        pK1[o] = k1; pK2[o] = k2; pK3[o] = k3;
      }
    }
  }
  __syncthreads();
  if (tid < 128) {                            // merge MFMA wr halves
    u64 k1 = redK[tid * 3 + 0], k2 = redK[tid * 3 + 1], k3 = redK[tid * 3 + 2];
    ins3(redK[(128 + tid) * 3 + 0], k1, k2, k3);
    ins3(redK[(128 + tid) * 3 + 1], k1, k2, k3);
    ins3(redK[(128 + tid) * 3 + 2], k1, k2, k3);
    size_t o = (size_t)cbx * NROW + rb0 + tid;
    pK1[o] = k1; pK2[o] = k2; pK3[o] = k3;
  }
}

// ---------------- k4: merge blocks + exact re-rank (R2 semantics, R10-validated) ------
__global__ __launch_bounds__(256) void merge_rerank_kernel(
    const float* __restrict__ z, const float* __restrict__ emb,
    const u64* __restrict__ pK1, const u64* __restrict__ pK2,
    const u64* __restrict__ pK3, const float* __restrict__ x2g,
    int* __restrict__ idx, float* __restrict__ out) {
  int n = blockIdx.x * 256 + threadIdx.x;
  u64 kmin = ~0ull;
  for (int blk = 0; blk < NBLK; ++blk) {
    u64 k = pK1[(size_t)blk * NROW + n];
    if (k < kmin) kmin = k;
  }
  float vcut = keyVal(kmin) + MARGIN;
  int cand[8]; int nc = 0;
  for (int blk = 0; blk < NBLK; ++blk) {
    size_t o = (size_t)blk * NROW + n;
    u64 k1 = pK1[o], k2 = pK2[o], k3 = pK3[o];
    if (keyVal(k1) <= vcut && nc < 8) cand[nc++] = (int)(k1 & 0xffffffffu);
    if (keyVal(k2) <= vcut && nc < 8) cand[nc++] = (int)(k2 & 0xffffffffu);
    if (keyVal(k3) <= vcut && nc < 8) cand[nc++] = (int)(k3 & 0xffffffffu);
  }
  int b = n >> 10, hw = n & 1023;
  const float* zp = z + (size_t)b * (CD * HWSZ) + hw;
  float x2 = x2g[n];
  float bs = INFINITY; int bi = 0x7fffffff;
  for (int c0 = 0; c0 < nc; ++c0) {
    int k = cand[c0];
    const float* ep = emb + (size_t)k * CD;
    float acc = 0.f;
    for (int c = 0; c < CD; ++c)                 // sequential fmaf chain == R2 dot
      acc = fmaf(zp[(size_t)c * HWSZ], ep[c], acc);
    float s = fmaf(-2.f, acc, x2);               // single rounding == np grid
    if (s < bs || (s == bs && k < bi)) { bs = s; bi = k; }
  }
  idx[n] = bi;
  out[QOFF + 1 + n] = (float)bi;
}

// ---------------- k5: gather quantized + loss partials (R2-proven) ----------------
__global__ __launch_bounds__(256) void gather_kernel(
    const float* __restrict__ z, const float* __restrict__ emb,
    const int* __restrict__ idx, float* __restrict__ out,
    float* __restrict__ lossPart) {
  __shared__ int sidx[64];
  __shared__ float swsum[4];
  int tid = threadIdx.x;
  int bid = blockIdx.x;
  int n0 = bid * 64;
  if (tid < 64) sidx[tid] = idx[n0 + tid];
  __syncthreads();
  int lane = tid & 63;
  int cw = tid >> 6;
  int b = n0 >> 10;
  int hw = (n0 & 1023) + lane;
  const float* erow = emb + (size_t)sidx[lane] * CD;
  float lacc = 0.f;
  for (int ci = 0; ci < 64; ++ci) {
    int c = cw * 64 + ci;
    float q = erow[c];
    size_t o = (size_t)b * (CD * HWSZ) + (size_t)c * HWSZ + hw;
    float zv = z[o];
    out[o] = q;
    float d = q - zv;
    lacc += d * d;
  }
#pragma unroll
  for (int off = 32; off > 0; off >>= 1) lacc += __shfl_down(lacc, off, 64);
  if (lane == 0) swsum[cw] = lacc;
  __syncthreads();
  if (tid == 0) lossPart[bid] = swsum[0] + swsum[1] + swsum[2] + swsum[3];
}

__global__ void loss_kernel(const float* __restrict__ lossPart, float* __restrict__ out) {
  if (threadIdx.x == 0) {
    double s = 0.0;
    for (int i = 0; i < 128; ++i) s += (double)lossPart[i];
    out[QOFF] = (float)(s * 1.25 / (double)(NROW * CD));
  }
}

extern "C" void kernel_launch(void* const* d_in, const int* in_sizes, int n_in,
                              void* d_out, int out_size, void* d_ws, size_t ws_size,
                              hipStream_t stream) {
  const float* z   = (const float*)d_in[0];
  const float* emb = (const float*)d_in[1];
  float* out = (float*)d_out;

  size_t pkBytes = (size_t)NBLK * NROW * 8;   // 4 MB each
  char* wp = (char*)d_ws;
  unsigned short* Ehi = (unsigned short*)wp;  wp += (size_t)KCODE * CD * 2;  // 4 MB
  unsigned short* Xhi = (unsigned short*)wp;  wp += (size_t)NROW * CD * 2;   // 4 MB
  u64* pK1 = (u64*)wp;                        wp += pkBytes;                 // 4 MB
  float* x2g = (float*)wp;                    wp += (size_t)NROW * 4;
  int* idx = (int*)wp;                        wp += (size_t)NROW * 4;
  float* lossPart = (float*)wp;               wp += 512;

  // pK2/pK3: ws if it fits, else d_out's 8MB quantized region (R12/R13-proven:
  // merge runs before gather overwrites; indices at QOFF+1 disjoint).
  u64 *pK2, *pK3;
  size_t used = (size_t)(wp - (char*)d_ws);
  if (ws_size >= used + 2 * pkBytes) {
    pK2 = (u64*)wp;
    pK3 = (u64*)(wp + pkBytes);
  } else {
    pK2 = (u64*)d_out;
    pK3 = (u64*)((char*)d_out + pkBytes);
  }

  hipLaunchKernelGGL(splitz_x2_kernel, dim3(NROW / 32), dim3(256), 0, stream, z, Xhi, x2g);
  hipLaunchKernelGGL(splite_kernel, dim3((KCODE * CD) / 256), dim3(256), 0, stream, emb, Ehi);
  hipLaunchKernelGGL(gemm_top3_kernel, dim3((KCODE / 128) * (NROW / 256)), dim3(512), 0, stream,
                     Ehi, Xhi, z, emb, pK1, pK2, pK3);
  hipLaunchKernelGGL(merge_rerank_kernel, dim3(NROW / 256), dim3(256), 0, stream,
                     z, emb, pK1, pK2, pK3, x2g, idx, out);
  hipLaunchKernelGGL(gather_kernel, dim3(NROW / 64), dim3(256), 0, stream,
                     z, emb, idx, out, lossPart);
  hipLaunchKernelGGL(loss_kernel, dim3(1), dim3(64), 0, stream, lossPart, out);
}